// Round 4
// baseline (688.884 us; speedup 1.0000x reference)
//
#include <hip/hip_runtime.h>

#define NB   256   // batch
#define NT   512   // time steps
#define NF   33    // features incl. flag channel
#define BOND 64
#define NOUT 32

typedef _Float16 h2 __attribute__((ext_vector_type(2)));
typedef float    f4 __attribute__((ext_vector_type(4)));

__device__ __forceinline__ float fdot2(h2 p, h2 q, float c) {
    return __builtin_amdgcn_fdot2(p, q, c, false);   // v_dot2_f32_f16
}

__device__ __forceinline__ h2 pk2(float a, float b) {
    auto r = __builtin_amdgcn_cvt_pkrtz(a, b);       // v_cvt_pkrtz_f16_f32
    return __builtin_bit_cast(h2, r);
}

// One chain step. Reads v_t from vbuf[pa], writes v_{t+1} to vbuf[pa^1].
// x for this step comes from SGPR-resident xs[] (loaded last step); x for the
// NEXT step is prefetched into xn[] via uniform (scalar) loads whose latency
// is hidden under the 128-dot2 phase.
__device__ __forceinline__ void do_step(int pa, const float* __restrict__ xnext,
                                        const h2 (&creg)[32][4],
                                        const float (&xs)[NF], float (&xn)[NF],
                                        float& vj, float (*__restrict__ vbuf)[BOND],
                                        int ib, int jl, bool writer)
{
    // v pairs for this lane's i-block (broadcast LDS read, 2-way alias = free)
    const float* vb = &vbuf[pa][ib << 3];
    f4 va = *(const f4*)vb;
    f4 vc = *(const f4*)(vb + 4);
    h2 vp0 = pk2(va.x, va.y), vp1 = pk2(va.z, va.w);
    h2 vp2 = pk2(vc.x, vc.y), vp3 = pk2(vc.z, vc.w);

    // prefetch next step's x: workgroup-uniform address -> scalar loads (SGPRs)
    #pragma unroll
    for (int k = 0; k < NF; ++k) xn[k] = xnext[k];

    // partial for (jl) over i in [8ib, 8ib+8): 4 independent accumulator chains
    float a0 = 0.f, a1 = 0.f, a2 = 0.f, a3 = 0.f;
    #pragma unroll
    for (int fq = 0; fq < 8; ++fq) {
        {
            const int ff = 4 * fq;
            float t0 = fdot2(vp0, creg[ff][0], 0.f);
            t0 = fdot2(vp1, creg[ff][1], t0);
            t0 = fdot2(vp2, creg[ff][2], t0);
            t0 = fdot2(vp3, creg[ff][3], t0);
            a0 = fmaf(xs[ff + 1], t0, a0);
        }
        {
            const int ff = 4 * fq + 1;
            float t0 = fdot2(vp0, creg[ff][0], 0.f);
            t0 = fdot2(vp1, creg[ff][1], t0);
            t0 = fdot2(vp2, creg[ff][2], t0);
            t0 = fdot2(vp3, creg[ff][3], t0);
            a1 = fmaf(xs[ff + 1], t0, a1);
        }
        {
            const int ff = 4 * fq + 2;
            float t0 = fdot2(vp0, creg[ff][0], 0.f);
            t0 = fdot2(vp1, creg[ff][1], t0);
            t0 = fdot2(vp2, creg[ff][2], t0);
            t0 = fdot2(vp3, creg[ff][3], t0);
            a2 = fmaf(xs[ff + 1], t0, a2);
        }
        {
            const int ff = 4 * fq + 3;
            float t0 = fdot2(vp0, creg[ff][0], 0.f);
            t0 = fdot2(vp1, creg[ff][1], t0);
            t0 = fdot2(vp2, creg[ff][2], t0);
            t0 = fdot2(vp3, creg[ff][3], t0);
            a3 = fmaf(xs[ff + 1], t0, a3);
        }
    }
    float acc = (a0 + a1) + (a2 + a3);

    // in-wave allreduce over the 8 i-blocks (lanes l^8, l^16, l^32)
    acc += __shfl_xor(acc, 8, 64);
    acc += __shfl_xor(acc, 16, 64);
    acc += __shfl_xor(acc, 32, 64);

    float vnew = fmaf(xs[0], vj, acc);    // exact fp32 identity (flag) channel
    vj = vnew;
    if (writer) vbuf[pa ^ 1][jl] = vnew;  // 8 lanes/wave publish this wave's 8 j's

    __syncthreads();
}

__global__ __launch_bounds__(512, 2)
void umps_chain(const float* __restrict__ x,
                const float* __restrict__ core,
                const float* __restrict__ alpha,
                const float* __restrict__ oc,
                float* __restrict__ out)
{
    const int tid  = (int)threadIdx.x;
    const int lane = tid & 63;
    const int w    = tid >> 6;               // 0..7
    const int ib   = lane >> 3;              // i-block: i in [8ib, 8ib+8)
    const int jl   = (w << 3) + (lane & 7);  // this lane's output j
    const int b    = (int)blockIdx.x;

    __shared__ float vbuf[2][BOND];

    // ---- core slice into registers: creg[ff][p] = (C[8ib+2p, ff+1, jl], C[8ib+2p+1, ff+1, jl]) ----
    h2 creg[32][4];
    {
        const float* cb = core + (size_t)(8 * ib) * (NF * BOND) + BOND + jl;
        #pragma unroll
        for (int p = 0; p < 4; ++p) {
            const float* c0 = cb + (size_t)(2 * p) * (NF * BOND);
            const float* c1 = cb + (size_t)(2 * p + 1) * (NF * BOND);
            #pragma unroll
            for (int ff = 0; ff < 32; ++ff)
                creg[ff][p] = pk2(c0[ff * BOND], c1[ff * BOND]);
        }
    }

    // ---- init carry ----
    float vj = alpha[jl];
    if (tid < BOND) vbuf[0][tid] = alpha[tid];

    // ---- x scalar pipeline: xs = x[b,0,:], loaded into SGPRs ----
    const float* xb = x + (size_t)b * (NT * NF);
    float xs[NF], xn[NF];
    #pragma unroll
    for (int k = 0; k < NF; ++k) xs[k] = xb[k];

    const bool writer = (ib == 0);

    __syncthreads();   // vbuf[0] ready

    #pragma unroll 1
    for (int t = 0; t < NT; t += 2) {
        const float* xp1 = xb + (size_t)(t + 1) * NF;                       // t+1 <= 511
        const float* xp2 = xb + (size_t)((t + 2 < NT) ? t + 2 : NT - 1) * NF;
        do_step(0, xp1, creg, xs, xn, vj, vbuf, ib, jl, writer);
        do_step(1, xp2, creg, xn, xs, vj, vbuf, ib, jl, writer);
    }
    // final v is in vbuf[0][:], synced by the barrier inside the last step

    // ---- epilogue: out[b,:] = v @ output_core (64 x 32) ----
    if (tid < NOUT) {
        float s = 0.f;
        #pragma unroll
        for (int jj = 0; jj < BOND; ++jj)
            s = fmaf(vbuf[0][jj], oc[jj * NOUT + tid], s);
        out[b * NOUT + tid] = s;
    }
}

extern "C" void kernel_launch(void* const* d_in, const int* in_sizes, int n_in,
                              void* d_out, int out_size, void* d_ws, size_t ws_size,
                              hipStream_t stream) {
    const float* x     = (const float*)d_in[0];  // (256, 512, 33) f32
    const float* core  = (const float*)d_in[1];  // (64, 33, 64) f32
    const float* alpha = (const float*)d_in[2];  // (64,) f32
    const float* oc    = (const float*)d_in[3];  // (64, 32) f32
    float* out = (float*)d_out;                  // (256, 32) f32

    umps_chain<<<dim3(NB), dim3(512), 0, stream>>>(x, core, alpha, oc, out);
}

// Round 5
// 672.630 us; speedup vs baseline: 1.0242x; 1.0242x over previous
//
#include <hip/hip_runtime.h>

#define NB   256   // batch
#define NT   512   // time steps
#define NF   33    // features incl. flag channel
#define BOND 64
#define NOUT 32

typedef _Float16 h2 __attribute__((ext_vector_type(2)));
typedef float    f4 __attribute__((ext_vector_type(4)));

__device__ __forceinline__ float fdot2(h2 p, h2 q, float c) {
    return __builtin_amdgcn_fdot2(p, q, c, false);   // v_dot2_f32_f16
}

__device__ __forceinline__ h2 pk2(float a, float b) {
    auto r = __builtin_amdgcn_cvt_pkrtz(a, b);       // v_cvt_pkrtz_f16_f32
    return __builtin_bit_cast(h2, r);
}

// One chain step. Reads v_t from vbuf[pa], writes v_{t+1} to vbuf[pa^1].
// x for this step comes from xs[] (loaded last step); x for the NEXT step is
// prefetched into xn[] early so its latency hides under the 128-dot2 phase.
__device__ __forceinline__ void do_step(int pa, const float* __restrict__ xnext,
                                        const h2 (&creg)[32][4],
                                        const float (&xs)[NF], float (&xn)[NF],
                                        float& vj, float (*__restrict__ vbuf)[BOND],
                                        int ib, int jl, bool writer)
{
    // v pairs for this lane's i-block (broadcast LDS read, 2-way alias = free)
    const float* vb = &vbuf[pa][ib << 3];
    f4 va = *(const f4*)vb;
    f4 vc = *(const f4*)(vb + 4);
    h2 vp0 = pk2(va.x, va.y), vp1 = pk2(va.z, va.w);
    h2 vp2 = pk2(vc.x, vc.y), vp3 = pk2(vc.z, vc.w);

    // prefetch next step's x (issued early, consumed next step)
    #pragma unroll
    for (int k = 0; k < NF; ++k) xn[k] = xnext[k];

    // partial for (jl) over i in [8ib, 8ib+8): 4 independent accumulator chains
    float a0 = 0.f, a1 = 0.f, a2 = 0.f, a3 = 0.f;
    #pragma unroll
    for (int fq = 0; fq < 8; ++fq) {
        {
            const int ff = 4 * fq;
            float t0 = fdot2(vp0, creg[ff][0], 0.f);
            t0 = fdot2(vp1, creg[ff][1], t0);
            t0 = fdot2(vp2, creg[ff][2], t0);
            t0 = fdot2(vp3, creg[ff][3], t0);
            a0 = fmaf(xs[ff + 1], t0, a0);
        }
        {
            const int ff = 4 * fq + 1;
            float t0 = fdot2(vp0, creg[ff][0], 0.f);
            t0 = fdot2(vp1, creg[ff][1], t0);
            t0 = fdot2(vp2, creg[ff][2], t0);
            t0 = fdot2(vp3, creg[ff][3], t0);
            a1 = fmaf(xs[ff + 1], t0, a1);
        }
        {
            const int ff = 4 * fq + 2;
            float t0 = fdot2(vp0, creg[ff][0], 0.f);
            t0 = fdot2(vp1, creg[ff][1], t0);
            t0 = fdot2(vp2, creg[ff][2], t0);
            t0 = fdot2(vp3, creg[ff][3], t0);
            a2 = fmaf(xs[ff + 1], t0, a2);
        }
        {
            const int ff = 4 * fq + 3;
            float t0 = fdot2(vp0, creg[ff][0], 0.f);
            t0 = fdot2(vp1, creg[ff][1], t0);
            t0 = fdot2(vp2, creg[ff][2], t0);
            t0 = fdot2(vp3, creg[ff][3], t0);
            a3 = fmaf(xs[ff + 1], t0, a3);
        }
    }
    float acc = (a0 + a1) + (a2 + a3);

    // in-wave allreduce over the 8 i-blocks (lanes l^8, l^16, l^32)
    acc += __shfl_xor(acc, 8, 64);
    acc += __shfl_xor(acc, 16, 64);
    acc += __shfl_xor(acc, 32, 64);

    float vnew = fmaf(xs[0], vj, acc);    // exact fp32 identity (flag) channel
    vj = vnew;
    if (writer) vbuf[pa ^ 1][jl] = vnew;  // 8 lanes/wave publish this wave's 8 j's

    __syncthreads();
}

// NOTE: 2nd launch-bounds arg is min waves/EU. (512,2) forced a 128-VGPR cap
// (2 co-resident 8-wave blocks) -> creg spilled to scratch (15.9 MB WRITE_SIZE
// in R4). (512,1) -> 2 waves/SIMD -> 256-VGPR budget; creg stays resident.
__global__ __launch_bounds__(512, 1)
void umps_chain(const float* __restrict__ x,
                const float* __restrict__ core,
                const float* __restrict__ alpha,
                const float* __restrict__ oc,
                float* __restrict__ out)
{
    const int tid  = (int)threadIdx.x;
    const int lane = tid & 63;
    const int w    = tid >> 6;               // 0..7
    const int ib   = lane >> 3;              // i-block: i in [8ib, 8ib+8)
    const int jl   = (w << 3) + (lane & 7);  // this lane's output j
    const int b    = (int)blockIdx.x;

    __shared__ float vbuf[2][BOND];

    // ---- core slice into registers: creg[ff][p] = (C[8ib+2p, ff+1, jl], C[8ib+2p+1, ff+1, jl]) ----
    h2 creg[32][4];
    {
        const float* cb = core + (size_t)(8 * ib) * (NF * BOND) + BOND + jl;
        #pragma unroll
        for (int p = 0; p < 4; ++p) {
            const float* c0 = cb + (size_t)(2 * p) * (NF * BOND);
            const float* c1 = cb + (size_t)(2 * p + 1) * (NF * BOND);
            #pragma unroll
            for (int ff = 0; ff < 32; ++ff)
                creg[ff][p] = pk2(c0[ff * BOND], c1[ff * BOND]);
        }
    }

    // ---- init carry ----
    float vj = alpha[jl];
    if (tid < BOND) vbuf[0][tid] = alpha[tid];

    // ---- x pipeline: xs = x[b,0,:] ----
    const float* xb = x + (size_t)b * (NT * NF);
    float xs[NF], xn[NF];
    #pragma unroll
    for (int k = 0; k < NF; ++k) xs[k] = xb[k];

    const bool writer = (ib == 0);

    __syncthreads();   // vbuf[0] ready

    #pragma unroll 1
    for (int t = 0; t < NT; t += 2) {
        const float* xp1 = xb + (size_t)(t + 1) * NF;                       // t+1 <= 511
        const float* xp2 = xb + (size_t)((t + 2 < NT) ? t + 2 : NT - 1) * NF;
        do_step(0, xp1, creg, xs, xn, vj, vbuf, ib, jl, writer);
        do_step(1, xp2, creg, xn, xs, vj, vbuf, ib, jl, writer);
    }
    // final v is in vbuf[0][:], synced by the barrier inside the last step

    // ---- epilogue: out[b,:] = v @ output_core (64 x 32) ----
    if (tid < NOUT) {
        float s = 0.f;
        #pragma unroll
        for (int jj = 0; jj < BOND; ++jj)
            s = fmaf(vbuf[0][jj], oc[jj * NOUT + tid], s);
        out[b * NOUT + tid] = s;
    }
}

extern "C" void kernel_launch(void* const* d_in, const int* in_sizes, int n_in,
                              void* d_out, int out_size, void* d_ws, size_t ws_size,
                              hipStream_t stream) {
    const float* x     = (const float*)d_in[0];  // (256, 512, 33) f32
    const float* core  = (const float*)d_in[1];  // (64, 33, 64) f32
    const float* alpha = (const float*)d_in[2];  // (64,) f32
    const float* oc    = (const float*)d_in[3];  // (64, 32) f32
    float* out = (float*)d_out;                  // (256, 32) f32

    umps_chain<<<dim3(NB), dim3(512), 0, stream>>>(x, core, alpha, oc, out);
}

// Round 6
// 596.401 us; speedup vs baseline: 1.1551x; 1.1278x over previous
//
#include <hip/hip_runtime.h>

#define NB   256   // batch
#define NT   512   // time steps
#define NF   33    // features incl. flag channel
#define NFP  36    // padded/rotated x row (floats; 144 B)
#define BOND 64
#define NOUT 32

typedef _Float16 h2 __attribute__((ext_vector_type(2)));
typedef float    f4 __attribute__((ext_vector_type(4)));

__device__ __forceinline__ float fdot2(h2 p, h2 q, float c) {
    return __builtin_amdgcn_fdot2(p, q, c, false);   // v_dot2_f32_f16
}

__device__ __forceinline__ h2 pk2(float a, float b) {
    auto r = __builtin_amdgcn_cvt_pkrtz(a, b);       // v_cvt_pkrtz_f16_f32
    return __builtin_bit_cast(h2, r);
}

// One chain step. Reads v_t from vbuf[pa], writes v_{t+1} to vbuf[pa^1].
// All LDS reads (v pairs + x row) issue together at the top; one lgkm wait
// covers them. No global traffic inside the loop.
__device__ __forceinline__ void do_step(int pa, int t,
                                        const h2 (&creg)[32][4],
                                        float& vj, float (*__restrict__ vbuf)[BOND],
                                        const float* __restrict__ xlds,
                                        int ib, int jl, bool writer)
{
    // v pairs for this lane's i-block (broadcast b128, 8 lanes/addr = free)
    const float* vb = &vbuf[pa][ib << 3];
    f4 va = *(const f4*)vb;
    f4 vc = *(const f4*)(vb + 4);

    // this step's x row (rotated layout: k<32 -> feature k+1, k=32 -> flag)
    const float* xr = xlds + t * NFP;
    f4 xq[8];
    #pragma unroll
    for (int k = 0; k < 8; ++k) xq[k] = *(const f4*)(xr + 4 * k);
    float x0 = xr[32];

    h2 vp0 = pk2(va.x, va.y), vp1 = pk2(va.z, va.w);
    h2 vp2 = pk2(vc.x, vc.y), vp3 = pk2(vc.z, vc.w);

    // partial for (jl) over i in [8ib, 8ib+8): 4 independent accumulator chains
    float a0 = 0.f, a1 = 0.f, a2 = 0.f, a3 = 0.f;
    #pragma unroll
    for (int fq = 0; fq < 8; ++fq) {
        {
            const int ff = 4 * fq;
            float t0 = fdot2(vp0, creg[ff][0], 0.f);
            t0 = fdot2(vp1, creg[ff][1], t0);
            t0 = fdot2(vp2, creg[ff][2], t0);
            t0 = fdot2(vp3, creg[ff][3], t0);
            a0 = fmaf(xq[fq][0], t0, a0);
        }
        {
            const int ff = 4 * fq + 1;
            float t0 = fdot2(vp0, creg[ff][0], 0.f);
            t0 = fdot2(vp1, creg[ff][1], t0);
            t0 = fdot2(vp2, creg[ff][2], t0);
            t0 = fdot2(vp3, creg[ff][3], t0);
            a1 = fmaf(xq[fq][1], t0, a1);
        }
        {
            const int ff = 4 * fq + 2;
            float t0 = fdot2(vp0, creg[ff][0], 0.f);
            t0 = fdot2(vp1, creg[ff][1], t0);
            t0 = fdot2(vp2, creg[ff][2], t0);
            t0 = fdot2(vp3, creg[ff][3], t0);
            a2 = fmaf(xq[fq][2], t0, a2);
        }
        {
            const int ff = 4 * fq + 3;
            float t0 = fdot2(vp0, creg[ff][0], 0.f);
            t0 = fdot2(vp1, creg[ff][1], t0);
            t0 = fdot2(vp2, creg[ff][2], t0);
            t0 = fdot2(vp3, creg[ff][3], t0);
            a3 = fmaf(xq[fq][3], t0, a3);
        }
    }
    float acc = (a0 + a1) + (a2 + a3);

    // in-wave allreduce over the 8 i-blocks (lanes l^8, l^16, l^32)
    acc += __shfl_xor(acc, 8, 64);
    acc += __shfl_xor(acc, 16, 64);
    acc += __shfl_xor(acc, 32, 64);

    float vnew = fmaf(x0, vj, acc);       // exact fp32 identity (flag) channel
    vj = vnew;
    if (writer) vbuf[pa ^ 1][jl] = vnew;  // 8 lanes/wave publish this wave's 8 j's

    __syncthreads();
}

// amdgpu_waves_per_eu(2,2): 2 waves/EU -> 256-VGPR budget. launch_bounds'
// 2nd arg failed to deliver this in R4/R5 (VGPR stuck at 128, 15.9 MB spill).
__global__ __launch_bounds__(512)
__attribute__((amdgpu_waves_per_eu(2, 2)))
void umps_chain(const float* __restrict__ x,
                const float* __restrict__ core,
                const float* __restrict__ alpha,
                const float* __restrict__ oc,
                float* __restrict__ out)
{
    const int tid  = (int)threadIdx.x;
    const int lane = tid & 63;
    const int w    = tid >> 6;               // 0..7
    const int ib   = lane >> 3;              // i-block: i in [8ib, 8ib+8)
    const int jl   = (w << 3) + (lane & 7);  // this lane's output j
    const int b    = (int)blockIdx.x;

    __shared__ __align__(16) float xlds[NT * NFP];   // 73728 B
    __shared__ float vbuf[2][BOND];

    // ---- stage this batch's x into LDS (one-time, rotated layout) ----
    const float* xb = x + (size_t)b * (NT * NF);
    for (int idx = tid; idx < NT * NF; idx += 512) {
        int t = idx / NF;
        int f = idx - t * NF;
        int k = (f == 0) ? 32 : (f - 1);
        xlds[t * NFP + k] = xb[idx];
    }

    // ---- core slice: creg[ff][p] = (C[8ib+2p, ff+1, jl], C[8ib+2p+1, ff+1, jl]) ----
    h2 creg[32][4];
    {
        const float* cb = core + (size_t)(8 * ib) * (NF * BOND) + BOND + jl;
        #pragma unroll
        for (int p = 0; p < 4; ++p) {
            const float* c0 = cb + (size_t)(2 * p) * (NF * BOND);
            const float* c1 = cb + (size_t)(2 * p + 1) * (NF * BOND);
            #pragma unroll
            for (int ff = 0; ff < 32; ++ff)
                creg[ff][p] = pk2(c0[ff * BOND], c1[ff * BOND]);
        }
    }

    // ---- init carry ----
    float vj = alpha[jl];
    if (tid < BOND) vbuf[0][tid] = alpha[tid];

    const bool writer = (ib == 0);

    __syncthreads();   // xlds + vbuf[0] ready

    #pragma unroll 1
    for (int t = 0; t < NT; t += 2) {
        do_step(0, t,     creg, vj, vbuf, xlds, ib, jl, writer);
        do_step(1, t + 1, creg, vj, vbuf, xlds, ib, jl, writer);
    }
    // final v is in vbuf[0][:], synced by the barrier inside the last step

    // ---- epilogue: out[b,:] = v @ output_core (64 x 32) ----
    if (tid < NOUT) {
        float s = 0.f;
        #pragma unroll
        for (int jj = 0; jj < BOND; ++jj)
            s = fmaf(vbuf[0][jj], oc[jj * NOUT + tid], s);
        out[b * NOUT + tid] = s;
    }
}

extern "C" void kernel_launch(void* const* d_in, const int* in_sizes, int n_in,
                              void* d_out, int out_size, void* d_ws, size_t ws_size,
                              hipStream_t stream) {
    const float* x     = (const float*)d_in[0];  // (256, 512, 33) f32
    const float* core  = (const float*)d_in[1];  // (64, 33, 64) f32
    const float* alpha = (const float*)d_in[2];  // (64,) f32
    const float* oc    = (const float*)d_in[3];  // (64, 32) f32
    float* out = (float*)d_out;                  // (256, 32) f32

    umps_chain<<<dim3(NB), dim3(512), 0, stream>>>(x, core, alpha, oc, out);
}